// Round 1
// baseline (879.797 us; speedup 1.0000x reference)
//
#include <hip/hip_runtime.h>
#include <hip/hip_bf16.h>

#define H    2048
#define NI   1408
#define NE   8
#define NTOK 2048
#define NIS  2816

typedef __bf16 bf16x8 __attribute__((ext_vector_type(8)));
typedef float  f32x4  __attribute__((ext_vector_type(4)));

// ---------------------------------------------------------------------------
// Gate: fp32 logits -> softmax -> top2 -> per-expert pair lists
// one wave per token, 4 tokens per block
// ---------------------------------------------------------------------------
__global__ __launch_bounds__(256)
void gate_kernel(const float* __restrict__ x, const float* __restrict__ gw,
                 float* __restrict__ topw, int* __restrict__ pairs,
                 int* __restrict__ cnt)
{
    int tok  = blockIdx.x * 4 + (threadIdx.x >> 6);
    int lane = threadIdx.x & 63;
    float acc[NE];
#pragma unroll
    for (int e = 0; e < NE; ++e) acc[e] = 0.f;
    const float* xr = x + (size_t)tok * H;
    for (int h = lane; h < H; h += 64) {
        float xv = xr[h];
#pragma unroll
        for (int e = 0; e < NE; ++e) acc[e] += xv * gw[e * H + h];
    }
#pragma unroll
    for (int e = 0; e < NE; ++e) {
        float v = acc[e];
        for (int off = 32; off; off >>= 1) v += __shfl_xor(v, off);
        acc[e] = v;
    }
    if (lane == 0) {
        float mx = acc[0];
#pragma unroll
        for (int e = 1; e < NE; ++e) mx = fmaxf(mx, acc[e]);
        float p[NE]; float s = 0.f;
#pragma unroll
        for (int e = 0; e < NE; ++e) { p[e] = __expf(acc[e] - mx); s += p[e]; }
        float inv = 1.f / s;
        int e1 = 0;
#pragma unroll
        for (int e = 1; e < NE; ++e) if (acc[e] > acc[e1]) e1 = e;  // first-index tie-break like lax.top_k
        int e2 = -1;
#pragma unroll
        for (int e = 0; e < NE; ++e) {
            if (e == e1) continue;
            if (e2 < 0 || acc[e] > acc[e2]) e2 = e;
        }
        topw[tok * 2 + 0] = p[e1] * inv;
        topw[tok * 2 + 1] = p[e2] * inv;
        int pos1 = atomicAdd(&cnt[e1], 1);
        pairs[e1 * NTOK + pos1] = tok * 2 + 0;   // pid = tok*2 + slot
        int pos2 = atomicAdd(&cnt[e2], 1);
        pairs[e2 * NTOK + pos2] = tok * 2 + 1;
    }
}

// ---------------------------------------------------------------------------
// GEMM: 128x128 block tile, BK=32, 4 waves (2x2), 4x4 mfma 16x16x32 per wave.
// LDS tiles stored [row][k] with row pad to 40 elems (80B: 16B aligned, even
// bank spread for b128 ops). B staged transposed via per-column scalar fp32
// loads (coalesced across lanes) + in-reg bf16 convert.
//   GU:     C = [silu(A@Bg) * (A@Bu)] -> bf16, optional row gather via pairs
//   !GU:    C = A@Bg -> fp32 plain store, or weighted atomicAdd (ATOMIC)
// ---------------------------------------------------------------------------
template<bool GU, bool GATHER, bool ATOMIC>
__global__ __launch_bounds__(256, 2)
void gemm_k(const void* __restrict__ Aptr, const float* __restrict__ Bg_,
            const float* __restrict__ Bu_, void* __restrict__ outp,
            const int* __restrict__ pairs, const int* __restrict__ cnt,
            const float* __restrict__ topw,
            int M, int K, int ldB, int ldOut)
{
    const int t    = threadIdx.x;
    const int lane = t & 63;
    const int wid  = t >> 6;
    const int wm   = wid >> 1, wn = wid & 1;
    const int e    = blockIdx.z;
    const int m0   = blockIdx.y * 128;
    const int n0   = blockIdx.x * 128;

    int count = M;
    if (GATHER) {
        count = cnt[e];
        if (m0 >= count) return;
    }
    const float* Bg = Bg_ + (size_t)e * K * ldB;
    const float* Bu = GU ? (Bu_ + (size_t)e * K * ldB) : nullptr;
    const int* plist = GATHER ? (pairs + (size_t)e * NTOK) : nullptr;

    __shared__ __align__(16) __bf16 lds[(GU ? 3 : 2) * 128 * 40];
    __bf16* At  = lds;
    __bf16* Btg = lds + 128 * 40;
    __bf16* Btu = GU ? (lds + 2 * 128 * 40) : nullptr;
    __shared__ int tile_pid[128];

    if (GATHER && t < 128) {
        int j = m0 + t;
        tile_pid[t] = (j < count) ? plist[j] : -1;
    }
    __syncthreads();

    // A staging source row (fixed across K loop)
    const int mrow = t >> 1;
    const int kh   = t & 1;          // which 16-elem half of BK
    size_t arow;
    if (GATHER) {
        int pid = tile_pid[mrow];
        if (pid < 0) pid = 0;        // every pid in [0,4096) is written, row 0 safe
        arow = GU ? (size_t)(pid >> 1) : (size_t)pid;
    } else {
        arow = (size_t)(m0 + mrow);
    }
    const float*  Af = (const float*)Aptr;
    const __bf16* Ab = (const __bf16*)Aptr;

    const int nc  = t & 127;         // B column within tile
    const int kh2 = t >> 7;

    f32x4 accg[4][4] = {};
    f32x4 accu[4][4] = {};

    for (int k0 = 0; k0 < K; k0 += 32) {
        __syncthreads();
        // ---- stage A (128 x 32) ----
        if constexpr (GU) {
            const float* src = Af + arow * (size_t)K + k0 + kh * 16;
            union { __bf16 h[16]; uint4 q[2]; } tmp;
#pragma unroll
            for (int i = 0; i < 4; ++i) {
                float4 v = ((const float4*)src)[i];
                tmp.h[i * 4 + 0] = (__bf16)v.x;
                tmp.h[i * 4 + 1] = (__bf16)v.y;
                tmp.h[i * 4 + 2] = (__bf16)v.z;
                tmp.h[i * 4 + 3] = (__bf16)v.w;
            }
            uint4* dst = (uint4*)(At + mrow * 40 + kh * 16);
            dst[0] = tmp.q[0];
            dst[1] = tmp.q[1];
        } else {
            const __bf16* src = Ab + arow * (size_t)K + k0 + kh * 16;
            uint4* dst = (uint4*)(At + mrow * 40 + kh * 16);
            dst[0] = ((const uint4*)src)[0];
            dst[1] = ((const uint4*)src)[1];
        }
        // ---- stage B transposed (32 x 128 -> [n][k]) ----
        {
            const float* bs = Bg + (size_t)(k0 + kh2 * 16) * ldB + n0 + nc;
            union { __bf16 h[16]; uint4 q[2]; } tb;
#pragma unroll
            for (int i = 0; i < 16; ++i) tb.h[i] = (__bf16)bs[(size_t)i * ldB];
            uint4* dst = (uint4*)(Btg + nc * 40 + kh2 * 16);
            dst[0] = tb.q[0]; dst[1] = tb.q[1];
            if constexpr (GU) {
                const float* bs2 = Bu + (size_t)(k0 + kh2 * 16) * ldB + n0 + nc;
#pragma unroll
                for (int i = 0; i < 16; ++i) tb.h[i] = (__bf16)bs2[(size_t)i * ldB];
                uint4* dst2 = (uint4*)(Btu + nc * 40 + kh2 * 16);
                dst2[0] = tb.q[0]; dst2[1] = tb.q[1];
            }
        }
        __syncthreads();
        // ---- compute ----
        bf16x8 a[4];
#pragma unroll
        for (int mi = 0; mi < 4; ++mi)
            a[mi] = *(const bf16x8*)(At + (wm * 64 + mi * 16 + (lane & 15)) * 40 + (lane >> 4) * 8);
#pragma unroll
        for (int ni = 0; ni < 4; ++ni) {
            bf16x8 bg = *(const bf16x8*)(Btg + (wn * 64 + ni * 16 + (lane & 15)) * 40 + (lane >> 4) * 8);
            bf16x8 bu = {};
            if constexpr (GU)
                bu = *(const bf16x8*)(Btu + (wn * 64 + ni * 16 + (lane & 15)) * 40 + (lane >> 4) * 8);
#pragma unroll
            for (int mi = 0; mi < 4; ++mi) {
                accg[mi][ni] = __builtin_amdgcn_mfma_f32_16x16x32_bf16(a[mi], bg, accg[mi][ni], 0, 0, 0);
                if constexpr (GU)
                    accu[mi][ni] = __builtin_amdgcn_mfma_f32_16x16x32_bf16(a[mi], bu, accu[mi][ni], 0, 0, 0);
            }
        }
    }

    // ---- epilogue ----
#pragma unroll
    for (int mi = 0; mi < 4; ++mi) {
#pragma unroll
        for (int r = 0; r < 4; ++r) {
            int row = wm * 64 + mi * 16 + (lane >> 4) * 4 + r;   // C row = (lane>>4)*4 + reg
            int pid = 0; bool valid = true;
            if constexpr (GATHER) { pid = tile_pid[row]; valid = (pid >= 0); }
#pragma unroll
            for (int ni = 0; ni < 4; ++ni) {
                int col = n0 + wn * 64 + ni * 16 + (lane & 15);  // C col = lane&15
                if constexpr (GU) {
                    if (valid) {
                        float g = accg[mi][ni][r];
                        float u = accu[mi][ni][r];
                        float hv = g / (1.f + __expf(-g)) * u;   // silu(g)*u
                        size_t orow = GATHER ? (size_t)pid : (size_t)(m0 + row);
                        ((__bf16*)outp)[orow * (size_t)ldOut + col] = (__bf16)hv;
                    }
                } else if constexpr (ATOMIC) {
                    if (valid) {
                        float w = topw[pid];
                        atomicAdd((float*)outp + (size_t)(pid >> 1) * ldOut + col,
                                  w * accg[mi][ni][r]);
                    }
                } else {
                    ((float*)outp)[(size_t)(m0 + row) * ldOut + col] = accg[mi][ni][r];
                }
            }
        }
    }
}

// ---------------------------------------------------------------------------
extern "C" void kernel_launch(void* const* d_in, const int* in_sizes, int n_in,
                              void* d_out, int out_size, void* d_ws, size_t ws_size,
                              hipStream_t stream)
{
    const float* x       = (const float*)d_in[0];
    const float* gate_w  = (const float*)d_in[1];
    const float* w_gate  = (const float*)d_in[2];
    const float* w_up    = (const float*)d_in[3];
    const float* w_down  = (const float*)d_in[4];
    const float* sw_gate = (const float*)d_in[5];
    const float* sw_up   = (const float*)d_in[6];
    const float* sw_down = (const float*)d_in[7];

    // workspace layout (~23.2 MB)
    char*   ws    = (char*)d_ws;
    float*  topw  = (float*)ws;                               // 16 KB
    int*    cnt   = (int*)(ws + 16384);                       // 32 B (padded)
    int*    pairs = (int*)(ws + 16384 + 128);                 // 64 KB
    __bf16* h_sh  = (__bf16*)(ws + 131072);                   // 2048*2816 bf16
    __bf16* h_rt  = (__bf16*)(ws + 131072 + (size_t)NTOK * NIS * 2); // 4096*1408 bf16

    hipMemsetAsync(cnt, 0, NE * sizeof(int), stream);

    gate_kernel<<<NTOK / 4, 256, 0, stream>>>(x, gate_w, topw, pairs, cnt);

    // shared expert: h_sh = silu(x@sw_gate)*(x@sw_up)
    gemm_k<true, false, false><<<dim3(NIS / 128, NTOK / 128, 1), 256, 0, stream>>>(
        x, sw_gate, sw_up, h_sh, nullptr, nullptr, nullptr, NTOK, H, NIS, NIS);

    // routed experts: h_rt[pid] = silu(x@w_gate[e])*(x@w_up[e]) for routed pairs
    gemm_k<true, true, false><<<dim3(NI / 128, NTOK / 128, NE), 256, 0, stream>>>(
        x, w_gate, w_up, h_rt, pairs, cnt, nullptr, NTOK, H, NI, NI);

    // shared down: d_out = h_sh @ sw_down (plain store initializes output)
    gemm_k<false, false, false><<<dim3(H / 128, NTOK / 128, 1), 256, 0, stream>>>(
        h_sh, sw_down, nullptr, d_out, nullptr, nullptr, nullptr, NTOK, NIS, H, H);

    // routed down: d_out[tok] += topw[pid] * (h_rt[pid] @ w_down[e])
    gemm_k<false, true, true><<<dim3(H / 128, NTOK / 128, NE), 256, 0, stream>>>(
        h_rt, w_down, nullptr, d_out, pairs, cnt, topw, NTOK, NI, H, H);
}

// Round 2
// 682.840 us; speedup vs baseline: 1.2884x; 1.2884x over previous
//
#include <hip/hip_runtime.h>
#include <hip/hip_bf16.h>

#define H    2048
#define NI   1408
#define NE   8
#define NTOK 2048
#define NIS  2816

typedef __bf16 bf16x8 __attribute__((ext_vector_type(8)));
typedef float  f32x4  __attribute__((ext_vector_type(4)));

#define ASYNC16(gp, lp) __builtin_amdgcn_global_load_lds( \
    (const __attribute__((address_space(1))) void*)(gp),  \
    (__attribute__((address_space(3))) void*)(lp), 16, 0, 0)

// ---------------------------------------------------------------------------
// Elementwise fp32 -> bf16 (x), 8 elems/thread
// ---------------------------------------------------------------------------
__global__ __launch_bounds__(256)
void cvt_kernel(const float* __restrict__ in, __bf16* __restrict__ out)
{
    size_t i = ((size_t)blockIdx.x * 256 + threadIdx.x) * 8;
    float4 v0 = *(const float4*)(in + i);
    float4 v1 = *(const float4*)(in + i + 4);
    union { __bf16 b[8]; uint4 u; } p;
    p.b[0] = (__bf16)v0.x; p.b[1] = (__bf16)v0.y;
    p.b[2] = (__bf16)v0.z; p.b[3] = (__bf16)v0.w;
    p.b[4] = (__bf16)v1.x; p.b[5] = (__bf16)v1.y;
    p.b[6] = (__bf16)v1.z; p.b[7] = (__bf16)v1.w;
    *(uint4*)(out + i) = p.u;
}

// ---------------------------------------------------------------------------
// Transpose-convert: in fp32 [K][N] (batched by z) -> out bf16 [N][K]
// 64x64 tiles via LDS; both global sides coalesced (float4 in, uint4 out)
// ---------------------------------------------------------------------------
__global__ __launch_bounds__(256)
void cvt_t_kernel(const float* __restrict__ in, __bf16* __restrict__ out,
                  int K, int N)
{
    const size_t zoff = (size_t)blockIdx.z * K * N;
    in  += zoff;
    out += zoff;
    const int n0 = blockIdx.x * 64;
    const int k0 = blockIdx.y * 64;
    __shared__ __bf16 tile[64][72];
    const int t = threadIdx.x;
    const int tr  = t >> 4;        // 0..15
    const int tc4 = (t & 15) * 4;  // col
#pragma unroll
    for (int i = 0; i < 4; ++i) {
        int k = i * 16 + tr;
        float4 v = *(const float4*)(in + (size_t)(k0 + k) * N + n0 + tc4);
        tile[k][tc4 + 0] = (__bf16)v.x;
        tile[k][tc4 + 1] = (__bf16)v.y;
        tile[k][tc4 + 2] = (__bf16)v.z;
        tile[k][tc4 + 3] = (__bf16)v.w;
    }
    __syncthreads();
    const int n = t >> 2, q = t & 3;
#pragma unroll
    for (int hh = 0; hh < 2; ++hh) {
        int qq = q + hh * 4;
        union { __bf16 b[8]; uint4 u; } pk;
#pragma unroll
        for (int j = 0; j < 8; ++j) pk.b[j] = tile[qq * 8 + j][n];
        *(uint4*)(out + (size_t)(n0 + n) * K + k0 + qq * 8) = pk.u;
    }
}

// ---------------------------------------------------------------------------
// Gate: fp32 logits -> softmax -> top2 -> per-expert pair lists
// ---------------------------------------------------------------------------
__global__ __launch_bounds__(256)
void gate_kernel(const float* __restrict__ x, const float* __restrict__ gw,
                 float* __restrict__ topw, int* __restrict__ pairs,
                 int* __restrict__ cnt)
{
    int tok  = blockIdx.x * 4 + (threadIdx.x >> 6);
    int lane = threadIdx.x & 63;
    float acc[NE];
#pragma unroll
    for (int e = 0; e < NE; ++e) acc[e] = 0.f;
    const float* xr = x + (size_t)tok * H;
    for (int h = lane; h < H; h += 64) {
        float xv = xr[h];
#pragma unroll
        for (int e = 0; e < NE; ++e) acc[e] += xv * gw[e * H + h];
    }
#pragma unroll
    for (int e = 0; e < NE; ++e) {
        float v = acc[e];
        for (int off = 32; off; off >>= 1) v += __shfl_xor(v, off);
        acc[e] = v;
    }
    if (lane == 0) {
        float mx = acc[0];
#pragma unroll
        for (int e = 1; e < NE; ++e) mx = fmaxf(mx, acc[e]);
        float p[NE]; float s = 0.f;
#pragma unroll
        for (int e = 0; e < NE; ++e) { p[e] = __expf(acc[e] - mx); s += p[e]; }
        float inv = 1.f / s;
        int e1 = 0;
#pragma unroll
        for (int e = 1; e < NE; ++e) if (acc[e] > acc[e1]) e1 = e;
        int e2 = -1;
#pragma unroll
        for (int e = 0; e < NE; ++e) {
            if (e == e1) continue;
            if (e2 < 0 || acc[e] > acc[e2]) e2 = e;
        }
        topw[tok * 2 + 0] = p[e1] * inv;
        topw[tok * 2 + 1] = p[e2] * inv;
        int pos1 = atomicAdd(&cnt[e1], 1);
        pairs[e1 * NTOK + pos1] = tok * 2 + 0;
        int pos2 = atomicAdd(&cnt[e2], 1);
        pairs[e2 * NTOK + pos2] = tok * 2 + 1;
    }
}

// ---------------------------------------------------------------------------
// Merged GU GEMM: z<NE -> routed expert z (gathered rows, out h_rt[pid]);
//                 z==NE -> shared expert (out h_sh).
// C = silu(A@Bg^T) * (A@Bu^T), A bf16 [.][H], B^T bf16 [n][H].
// 128x128x32 tile, global_load_lds(16B) staging, 4 waves, 4x4 mfma 16x16x32.
// ---------------------------------------------------------------------------
__global__ __launch_bounds__(256, 2)
void gu_kernel(const __bf16* __restrict__ xb,
               const __bf16* __restrict__ wgT, const __bf16* __restrict__ wuT,
               const __bf16* __restrict__ swgT, const __bf16* __restrict__ swuT,
               __bf16* __restrict__ h_sh, __bf16* __restrict__ h_rt,
               const int* __restrict__ pairs, const int* __restrict__ cnt)
{
    const int t = threadIdx.x, lane = t & 63;
    const int wid = t >> 6, wm = wid >> 1, wn = wid & 1;
    const int e = blockIdx.z;
    const bool routed = (e < NE);
    const int m0 = blockIdx.y * 128, n0 = blockIdx.x * 128;

    int count = NTOK;
    const __bf16 *Bg, *Bu;
    __bf16* outp;
    int ldO;
    if (routed) {
        if (n0 >= NI) return;
        count = cnt[e];
        if (m0 >= count) return;
        Bg = wgT + (size_t)e * NI * H;
        Bu = wuT + (size_t)e * NI * H;
        outp = h_rt; ldO = NI;
    } else {
        Bg = swgT; Bu = swuT; outp = h_sh; ldO = NIS;
    }

    __shared__ __align__(16) __bf16 At[128 * 32], Btg[128 * 32], Btu[128 * 32];
    __shared__ int tile_pid[128];
    if (t < 128) {
        int j = m0 + t;
        tile_pid[t] = routed ? ((j < count) ? pairs[e * NTOK + j] : -1) : j;
    }
    __syncthreads();

    const int r = t >> 2, c = t & 3;
    size_t ar0, ar1;
    if (routed) {
        int p0 = tile_pid[r];      if (p0 < 0) p0 = 0;
        int p1 = tile_pid[r + 64]; if (p1 < 0) p1 = 0;
        ar0 = (size_t)(p0 >> 1); ar1 = (size_t)(p1 >> 1);
    } else {
        ar0 = (size_t)(m0 + r); ar1 = (size_t)(m0 + r + 64);
    }
    const __bf16* a0 = xb + ar0 * H + c * 8;
    const __bf16* a1 = xb + ar1 * H + c * 8;
    const __bf16* g0 = Bg + (size_t)(n0 + r) * H + c * 8;
    const __bf16* g1 = Bg + (size_t)(n0 + r + 64) * H + c * 8;
    const __bf16* u0 = Bu + (size_t)(n0 + r) * H + c * 8;
    const __bf16* u1 = Bu + (size_t)(n0 + r + 64) * H + c * 8;
    __bf16* lA0 = At  + t * 8;  __bf16* lA1 = At  + (256 + t) * 8;
    __bf16* lG0 = Btg + t * 8;  __bf16* lG1 = Btg + (256 + t) * 8;
    __bf16* lU0 = Btu + t * 8;  __bf16* lU1 = Btu + (256 + t) * 8;

    f32x4 accg[4][4] = {};
    f32x4 accu[4][4] = {};

    for (int k0 = 0; k0 < H; k0 += 32) {
        __syncthreads();
        ASYNC16(a0 + k0, lA0); ASYNC16(a1 + k0, lA1);
        ASYNC16(g0 + k0, lG0); ASYNC16(g1 + k0, lG1);
        ASYNC16(u0 + k0, lU0); ASYNC16(u1 + k0, lU1);
        __syncthreads();
        bf16x8 a[4];
#pragma unroll
        for (int mi = 0; mi < 4; ++mi)
            a[mi] = *(const bf16x8*)(At + (wm * 64 + mi * 16 + (lane & 15)) * 32 + (lane >> 4) * 8);
#pragma unroll
        for (int ni = 0; ni < 4; ++ni) {
            bf16x8 bg = *(const bf16x8*)(Btg + (wn * 64 + ni * 16 + (lane & 15)) * 32 + (lane >> 4) * 8);
            bf16x8 bu = *(const bf16x8*)(Btu + (wn * 64 + ni * 16 + (lane & 15)) * 32 + (lane >> 4) * 8);
#pragma unroll
            for (int mi = 0; mi < 4; ++mi) {
                accg[mi][ni] = __builtin_amdgcn_mfma_f32_16x16x32_bf16(a[mi], bg, accg[mi][ni], 0, 0, 0);
                accu[mi][ni] = __builtin_amdgcn_mfma_f32_16x16x32_bf16(a[mi], bu, accu[mi][ni], 0, 0, 0);
            }
        }
    }

#pragma unroll
    for (int mi = 0; mi < 4; ++mi) {
#pragma unroll
        for (int rr = 0; rr < 4; ++rr) {
            int row = wm * 64 + mi * 16 + (lane >> 4) * 4 + rr;
            int pid = tile_pid[row];
            if (routed && pid < 0) continue;
            size_t orow = routed ? (size_t)pid : (size_t)(m0 + row);
#pragma unroll
            for (int ni = 0; ni < 4; ++ni) {
                int col = n0 + wn * 64 + ni * 16 + (lane & 15);
                float g = accg[mi][ni][rr];
                float u = accu[mi][ni][rr];
                float hv = g / (1.f + __expf(-g)) * u;
                outp[orow * (size_t)ldO + col] = (__bf16)hv;
            }
        }
    }
}

// ---------------------------------------------------------------------------
// Merged down GEMM, all-atomic epilogue into zero-initialized d_out:
//  z<NE : routed expert z: d_out[tok] += topw[pid] * (h_rt[pid] @ w_down[e])
//  z==NE: shared, K-half 0 ; z==NE+1: shared, K-half 1 (split-K, w=1)
// ---------------------------------------------------------------------------
__global__ __launch_bounds__(256, 2)
void down_kernel(const __bf16* __restrict__ h_sh, const __bf16* __restrict__ h_rt,
                 const __bf16* __restrict__ swdT, const __bf16* __restrict__ wdT,
                 float* __restrict__ out,
                 const int* __restrict__ pairs, const int* __restrict__ cnt,
                 const float* __restrict__ topw)
{
    const int t = threadIdx.x, lane = t & 63;
    const int wid = t >> 6, wm = wid >> 1, wn = wid & 1;
    const int e = blockIdx.z;
    const bool routed = (e < NE);
    const int m0 = blockIdx.y * 128, n0 = blockIdx.x * 128;

    int count = NTOK, K, lda, koff = 0;
    const __bf16 *A, *B;
    if (routed) {
        count = cnt[e];
        if (m0 >= count) return;
        A = h_rt; lda = NI; K = NI;
        B = wdT + (size_t)e * H * NI;
    } else {
        A = h_sh; lda = NIS; K = NI;          // split-K: 2816 = 2*1408
        koff = (e == NE) ? 0 : NI;
        B = swdT;
    }

    __shared__ __align__(16) __bf16 At[128 * 32], Bt[128 * 32];
    __shared__ int tile_pid[128];
    if (t < 128) {
        int j = m0 + t;
        tile_pid[t] = routed ? ((j < count) ? pairs[e * NTOK + j] : -1) : j;
    }
    __syncthreads();

    const int r = t >> 2, c = t & 3;
    size_t ar0, ar1;
    if (routed) {
        int p0 = tile_pid[r];      if (p0 < 0) p0 = 0;
        int p1 = tile_pid[r + 64]; if (p1 < 0) p1 = 0;
        ar0 = (size_t)p0; ar1 = (size_t)p1;
    } else {
        ar0 = (size_t)(m0 + r); ar1 = (size_t)(m0 + r + 64);
    }
    const __bf16* a0 = A + ar0 * lda + koff + c * 8;
    const __bf16* a1 = A + ar1 * lda + koff + c * 8;
    const __bf16* b0 = B + (size_t)(n0 + r) * lda + koff + c * 8;
    const __bf16* b1 = B + (size_t)(n0 + r + 64) * lda + koff + c * 8;
    __bf16* lA0 = At + t * 8;  __bf16* lA1 = At + (256 + t) * 8;
    __bf16* lB0 = Bt + t * 8;  __bf16* lB1 = Bt + (256 + t) * 8;

    f32x4 acc[4][4] = {};

    for (int k0 = 0; k0 < K; k0 += 32) {
        __syncthreads();
        ASYNC16(a0 + k0, lA0); ASYNC16(a1 + k0, lA1);
        ASYNC16(b0 + k0, lB0); ASYNC16(b1 + k0, lB1);
        __syncthreads();
        bf16x8 a[4];
#pragma unroll
        for (int mi = 0; mi < 4; ++mi)
            a[mi] = *(const bf16x8*)(At + (wm * 64 + mi * 16 + (lane & 15)) * 32 + (lane >> 4) * 8);
#pragma unroll
        for (int ni = 0; ni < 4; ++ni) {
            bf16x8 b = *(const bf16x8*)(Bt + (wn * 64 + ni * 16 + (lane & 15)) * 32 + (lane >> 4) * 8);
#pragma unroll
            for (int mi = 0; mi < 4; ++mi)
                acc[mi][ni] = __builtin_amdgcn_mfma_f32_16x16x32_bf16(a[mi], b, acc[mi][ni], 0, 0, 0);
        }
    }

#pragma unroll
    for (int mi = 0; mi < 4; ++mi) {
#pragma unroll
        for (int rr = 0; rr < 4; ++rr) {
            int row = wm * 64 + mi * 16 + (lane >> 4) * 4 + rr;
            int pid = tile_pid[row];
            if (routed && pid < 0) continue;
            size_t tok; float w;
            if (routed) { tok = (size_t)(pid >> 1); w = topw[pid]; }
            else        { tok = (size_t)(m0 + row); w = 1.f; }
#pragma unroll
            for (int ni = 0; ni < 4; ++ni) {
                int col = n0 + wn * 64 + ni * 16 + (lane & 15);
                atomicAdd(out + tok * H + col, w * acc[mi][ni][rr]);
            }
        }
    }
}

// ---------------------------------------------------------------------------
extern "C" void kernel_launch(void* const* d_in, const int* in_sizes, int n_in,
                              void* d_out, int out_size, void* d_ws, size_t ws_size,
                              hipStream_t stream)
{
    const float* x       = (const float*)d_in[0];
    const float* gate_w  = (const float*)d_in[1];
    const float* w_gate  = (const float*)d_in[2];
    const float* w_up    = (const float*)d_in[3];
    const float* w_down  = (const float*)d_in[4];
    const float* sw_gate = (const float*)d_in[5];
    const float* sw_up   = (const float*)d_in[6];
    const float* sw_down = (const float*)d_in[7];

    // workspace layout (151.1 MB total)
    char*   ws    = (char*)d_ws;
    float*  topw  = (float*)ws;                          // 16 KB
    int*    cnt   = (int*)(ws + 16384);                  // 128 B
    int*    pairs = (int*)(ws + 16512);                  // 64 KB
    __bf16* xb    = (__bf16*)(ws + 131072);              // 8.39 MB
    __bf16* h_sh  = (__bf16*)(ws + 8519680);             // 11.53 MB
    __bf16* h_rt  = (__bf16*)(ws + 20054016);            // 11.53 MB
    __bf16* swgT  = (__bf16*)(ws + 31588352);            // 11.53 MB
    __bf16* swuT  = (__bf16*)(ws + 43122688);            // 11.53 MB
    __bf16* swdT  = (__bf16*)(ws + 54657024);            // 11.53 MB
    __bf16* wgT   = (__bf16*)(ws + 66191360);            // 46.14 MB
    __bf16* wuT   = (__bf16*)(ws + 112328704);           // 46.14 MB
    __bf16* wdT   = wgT;  // aliased: converted AFTER gu_kernel finished with wgT

    hipMemsetAsync(cnt, 0, NE * sizeof(int), stream);
    hipMemsetAsync(d_out, 0, (size_t)NTOK * H * sizeof(float), stream);

    // fp32 -> bf16 (+transpose for weights)
    cvt_kernel<<<NTOK * H / 2048, 256, 0, stream>>>(x, xb);
    cvt_t_kernel<<<dim3(NIS / 64, H / 64, 1), 256, 0, stream>>>(sw_gate, swgT, H, NIS);
    cvt_t_kernel<<<dim3(NIS / 64, H / 64, 1), 256, 0, stream>>>(sw_up,   swuT, H, NIS);
    cvt_t_kernel<<<dim3(H / 64, NIS / 64, 1), 256, 0, stream>>>(sw_down, swdT, NIS, H);
    cvt_t_kernel<<<dim3(NI / 64, H / 64, NE), 256, 0, stream>>>(w_gate,  wgT,  H, NI);
    cvt_t_kernel<<<dim3(NI / 64, H / 64, NE), 256, 0, stream>>>(w_up,    wuT,  H, NI);

    gate_kernel<<<NTOK / 4, 256, 0, stream>>>(x, gate_w, topw, pairs, cnt);

    // merged GU: z=0..7 routed, z=8 shared
    gu_kernel<<<dim3(NIS / 128, NTOK / 128, NE + 1), 256, 0, stream>>>(
        xb, wgT, wuT, swgT, swuT, h_sh, h_rt, pairs, cnt);

    // convert w_down now (aliases wgT region, safe after gu_kernel)
    cvt_t_kernel<<<dim3(H / 64, NI / 64, NE), 256, 0, stream>>>(w_down, wdT, NI, H);

    // merged down: z=0..7 routed (atomic, weighted), z=8,9 shared split-K
    down_kernel<<<dim3(H / 128, NTOK / 128, NE + 2), 256, 0, stream>>>(
        h_sh, h_rt, swdT, wdT, (float*)d_out, pairs, cnt, topw);
}